// Round 5
// baseline (1623.664 us; speedup 1.0000x reference)
//
#include <hip/hip_runtime.h>

#define Bz 512
#define Tz 20
#define NOBJz 36
#define Dz 2048
#define EMBz 300
#define Ez 512
#define HMz 1024
#define HOz 256
#define KXM 832     // E + EMB = 812 padded to x64
#define KXO 1344    // 2E + EMB = 1324 padded to x64
#define NBLK 160    // persistent grid: 128 mask + 32 obj, <= 256 CUs so all co-resident

typedef short v8s __attribute__((ext_vector_type(8)));
typedef float v4f __attribute__((ext_vector_type(4)));
typedef unsigned short u16;

__device__ __forceinline__ float sigf(float x) { return 1.f / (1.f + __expf(-x)); }
__device__ __forceinline__ float tanhfast(float x) { return 2.f * sigf(2.f * x) - 1.f; }

__device__ __forceinline__ u16 f2bf(float f) {
    union { float f; unsigned u; } v; v.f = f;
    unsigned u = v.u;
    u += 0x7FFFu + ((u >> 16) & 1u);   // RNE
    return (u16)(u >> 16);
}
__device__ __forceinline__ float bf2f(u16 h) {
    union { unsigned u; float f; } v; v.u = ((unsigned)h) << 16;
    return v.f;
}

// =================== prologue kernels ===================

__global__ void obj_mask_kernel(const float* __restrict__ obj_enc, float* __restrict__ mask) {
    int bn = blockIdx.x, lane = threadIdx.x;
    const float* row = obj_enc + (size_t)bn * Dz;
    float s = 0.f;
    for (int d = lane; d < Dz; d += 64) s += fabsf(row[d]);
    for (int off = 32; off > 0; off >>= 1) s += __shfl_down(s, off);
    if (lane == 0) mask[bn] = (s > 0.f) ? 1.f : 0.f;
}

__global__ void meanim_kernel(const float* __restrict__ obj_enc, const float* __restrict__ mask,
                              u16* __restrict__ meanim_bf) {
    int idx = blockIdx.x * 256 + threadIdx.x;
    if (idx >= Bz * Dz) return;
    int b = idx / Dz, d = idx - b * Dz;
    float s = 0.f, cnt = 0.f;
    for (int n = 0; n < NOBJz; ++n) {
        float m = mask[b * NOBJz + n];
        cnt += m;
        s += obj_enc[((size_t)b * NOBJz + n) * Dz + d] * m;
    }
    meanim_bf[idx] = f2bf(s / fmaxf(cnt, 1e-9f));
}

// fp32 -> bf16 weight convert, optional column slice, zero pad, optional gate-interleave
__global__ void convert_pad(u16* __restrict__ dst, const float* __restrict__ src,
                            int rows, int src_cols, int ld_src, int col0, int dst_ld, int permH) {
    int idx = blockIdx.x * 256 + threadIdx.x;
    if (idx >= rows * dst_ld) return;
    int rp = idx / dst_ld, c = idx - rp * dst_ld;
    int n = rp;
    if (permH) { int g = (rp >> 4) & 3, u = (rp >> 6) * 16 + (rp & 15); n = g * permH + u; }
    dst[idx] = (c < src_cols) ? f2bf(src[(size_t)n * ld_src + col0 + c]) : (u16)0;
}

__global__ void bias_perm(float* __restrict__ dst, const float* __restrict__ src, int H) {
    int r = blockIdx.x * 256 + threadIdx.x;
    if (r >= 4 * H) return;
    int g = (r >> 4) & 3, u = (r >> 6) * 16 + (r & 15);
    dst[r] = src[g * H + u];
}

__global__ void assemble_Xm(u16* __restrict__ X, const float* __restrict__ qzm,
                            const int* __restrict__ x, const float* __restrict__ emd) {
    int idx = blockIdx.x * 256 + threadIdx.x;
    if (idx >= Tz * Bz * KXM) return;
    int r = idx / KXM, c = idx - r * KXM;
    int t = r / Bz, b = r - t * Bz;
    float v;
    if (c < Ez)             v = (t > 0) ? qzm[((size_t)b * Tz + (t - 1)) * Ez + c] : 0.f;
    else if (c < Ez + EMBz) { int xv = x[b * Tz + t]; v = emd[(size_t)xv * EMBz + (c - Ez)]; }
    else                    v = 0.f;
    X[idx] = f2bf(v);
}

__global__ void assemble_Xo(u16* __restrict__ X, const float* __restrict__ qzm,
                            const float* __restrict__ qzo, const int* __restrict__ x,
                            const float* __restrict__ emd) {
    int idx = blockIdx.x * 256 + threadIdx.x;
    if (idx >= Tz * Bz * KXO) return;
    int r = idx / KXO, c = idx - r * KXO;
    int t = r / Bz, b = r - t * Bz;
    float v;
    if (c < Ez)                 v = qzm[((size_t)b * Tz + t) * Ez + c];
    else if (c < 2 * Ez)        v = (t > 0) ? qzo[((size_t)b * Tz + (t - 1)) * Ez + (c - Ez)] : 0.f;
    else if (c < 2 * Ez + EMBz) { int xv = x[b * Tz + t]; v = emd[(size_t)xv * EMBz + (c - 2 * Ez)]; }
    else                        v = 0.f;
    X[idx] = f2bf(v);
}

// =================== MFMA GEMM core (128x128 tile, BK=64, global_load_lds, XOR swizzle) ===================

__device__ __forceinline__ void mma128(
    const u16* __restrict__ A, int lda, const u16* __restrict__ W, int ldw, int K,
    int bm, int bn, u16* As, u16* Ws, v4f (&acc)[4][4]) {
    const int tid = threadIdx.x;
    const int lane = tid & 63, w = tid >> 6;
    const int wm = w >> 1, wn = w & 1;
    const int r15 = lane & 15, quad = lane >> 4;
    const int lrow = lane >> 3;                 // 0..7 within chunk
    const int lcol = ((lane & 7) ^ lrow) * 8;   // swizzled source column (elements)
    for (int k0 = 0; k0 < K; k0 += 64) {
        const u16* gA = A + (size_t)bm * lda + k0;
        const u16* gW = W + (size_t)bn * ldw + k0;
#pragma unroll
        for (int c = 0; c < 4; ++c) {
            int chunk = w * 4 + c;              // 16 chunks of 8 rows each
            int row = chunk * 8 + lrow;
            __builtin_amdgcn_global_load_lds(
                (const __attribute__((address_space(1))) unsigned int*)(gA + (size_t)row * lda + lcol),
                (__attribute__((address_space(3))) unsigned int*)(As + chunk * 512), 16, 0, 0);
            __builtin_amdgcn_global_load_lds(
                (const __attribute__((address_space(1))) unsigned int*)(gW + (size_t)row * ldw + lcol),
                (__attribute__((address_space(3))) unsigned int*)(Ws + chunk * 512), 16, 0, 0);
        }
        __syncthreads();
#pragma unroll
        for (int kk = 0; kk < 64; kk += 32) {
            v8s a[4], b[4];
#pragma unroll
            for (int i = 0; i < 4; ++i) {
                int r = wm * 64 + 16 * i + r15;
                a[i] = *(const v8s*)&As[r * 64 + (((kk >> 3) + quad) ^ (r15 & 7)) * 8];
            }
#pragma unroll
            for (int j = 0; j < 4; ++j) {
                int r = wn * 64 + 16 * j + r15;
                b[j] = *(const v8s*)&Ws[r * 64 + (((kk >> 3) + quad) ^ (r15 & 7)) * 8];
            }
#pragma unroll
            for (int i = 0; i < 4; ++i)
#pragma unroll
                for (int j = 0; j < 4; ++j)
                    acc[i][j] = __builtin_amdgcn_mfma_f32_16x16x32_bf16(a[i], b[j], acc[i][j], 0, 0, 0);
        }
        __syncthreads();
    }
}

// generic GEMM: C(M,N) = A @ W^T (+bias[col]) (+addR bf16[row&mask][col]) ; out fp32 or bf16
__global__ __launch_bounds__(256) void gemm128(
    const u16* __restrict__ A, int lda, const u16* __restrict__ W, int ldw,
    void* __restrict__ Cv, int ldc, int K,
    const float* __restrict__ bias, const u16* __restrict__ addR, unsigned addR_mask, int out_bf16) {
    __shared__ u16 As[128 * 64];
    __shared__ u16 Ws[128 * 64];
    v4f acc[4][4] = {};
    const int bm = blockIdx.y * 128, bn = blockIdx.x * 128;
    mma128(A, lda, W, ldw, K, bm, bn, As, Ws, acc);
    const int tid = threadIdx.x, lane = tid & 63, w = tid >> 6;
    const int wm = w >> 1, wn = w & 1, r15 = lane & 15, quad = lane >> 4;
    float* Cf = (float*)Cv;
    u16* Cb = (u16*)Cv;
#pragma unroll
    for (int i = 0; i < 4; ++i)
#pragma unroll
        for (int j = 0; j < 4; ++j) {
            int col = bn + wn * 64 + 16 * j + r15;
            float bv = bias ? bias[col] : 0.f;
#pragma unroll
            for (int r = 0; r < 4; ++r) {
                int row = bm + wm * 64 + 16 * i + quad * 4 + r;
                float v = acc[i][j][r] + bv;
                if (addR) v += bf2f(addR[(size_t)(row & addR_mask) * ldc + col]);
                if (out_bf16) Cb[(size_t)row * ldc + col] = f2bf(v);
                else          Cf[(size_t)row * ldc + col] = v;
            }
        }
}

// =================== persistent recurrence with hand-rolled device-scope barrier ===================
// Release: __syncthreads (drain stores to L2) -> thread0 __threadfence (L2 writeback) + atomicAdd arrive.
// Acquire: after spin, __syncthreads -> ALL threads __threadfence (invalidate stale L1/L2 lines).
__device__ __forceinline__ void grid_barrier(unsigned* cnt, unsigned target) {
    __syncthreads();
    if (threadIdx.x == 0) {
        __threadfence();                       // release: flush this block's writes device-wide
        atomicAdd(cnt, 1u);
        while (atomicAdd(cnt, 0u) < target) {} // coherent spin (device-scope atomic read)
    }
    __syncthreads();
    __threadfence();                           // acquire: invalidate before reading peers' writes
}

// 160 blocks: [0,128) mask LSTM (M=512 x N=4096, K=1024), [128,160) obj LSTM (M=512 x N=1024, K=256).
// Cell state c lives in 16 VGPRs per thread for the whole sequence.
__global__ __launch_bounds__(256) void step_persist(
    u16* __restrict__ H_m, const u16* __restrict__ Whh_m, const u16* __restrict__ Gm,
    u16* __restrict__ H_o, const u16* __restrict__ Whh_o, const u16* __restrict__ Go,
    unsigned* __restrict__ barrier_cnt) {
    __shared__ u16 As[128 * 64];
    __shared__ u16 Ws[128 * 64];
    const int bx = blockIdx.x;
    u16* Hbase;
    const u16 *W, *G;
    int bm, bn, H, K, N4;
    if (bx < 128) {
        bm = (bx >> 5) * 128; bn = (bx & 31) * 128;
        Hbase = H_m; W = Whh_m; G = Gm; H = HMz; K = HMz; N4 = 4 * HMz;
    } else {
        int lx = bx - 128;
        bm = (lx >> 3) * 128; bn = (lx & 7) * 128;
        Hbase = H_o; W = Whh_o; G = Go; H = HOz; K = HOz; N4 = 4 * HOz;
    }
    const int tid = threadIdx.x, lane = tid & 63, w = tid >> 6;
    const int wm = w >> 1, wn = w & 1, r15 = lane & 15, quad = lane >> 4;
    const int u = ((bn + wn * 64) >> 6) * 16 + r15;
    float cst[4][4];
#pragma unroll
    for (int i = 0; i < 4; ++i)
#pragma unroll
        for (int r = 0; r < 4; ++r) cst[i][r] = 0.f;

    for (int t = 0; t < Tz; ++t) {
        v4f acc[4][4] = {};
        if (t > 0)
            mma128(Hbase + (size_t)(t - 1) * Bz * H, H, W, H, K, bm, bn, As, Ws, acc);
        const u16* Gt = G + (size_t)t * Bz * N4;
        u16* Ht = Hbase + (size_t)t * Bz * H;
#pragma unroll
        for (int i = 0; i < 4; ++i)
#pragma unroll
            for (int r = 0; r < 4; ++r) {
                int b = bm + wm * 64 + 16 * i + quad * 4 + r;
                size_t gb = (size_t)b * N4 + bn + wn * 64 + r15;
                float gi = acc[i][0][r] + bf2f(Gt[gb]);
                float gf = acc[i][1][r] + bf2f(Gt[gb + 16]);
                float gg = acc[i][2][r] + bf2f(Gt[gb + 32]);
                float go = acc[i][3][r] + bf2f(Gt[gb + 48]);
                float cn = sigf(gf) * cst[i][r] + sigf(gi) * tanhfast(gg);
                cst[i][r] = cn;
                Ht[(size_t)b * H + u] = f2bf(sigf(go) * tanhfast(cn));
            }
        if (t < Tz - 1)
            grid_barrier(barrier_cnt, (unsigned)NBLK * (unsigned)(t + 1));
        // final step: kernel completion + stream order make H visible to the FC GEMMs
    }
}

// =================== KL reduce ===================
__global__ __launch_bounds__(256) void kl_kernel(
    const float* __restrict__ outs_m, const float* __restrict__ outs_o,
    const float* __restrict__ qmm, const float* __restrict__ qlm,
    const float* __restrict__ qmo, const float* __restrict__ qlo,
    const int* __restrict__ x, float* __restrict__ out) {
    int b = blockIdx.x, tid = threadIdx.x;
    float total = 0.f;
    for (int t = 0; t < Tz; ++t) {
        int xv = x[b * Tz + t];
        if (xv == 0 || xv == 2) continue;
        const float* pm = outs_m + ((size_t)t * Bz + b) * 1024;
        const float* po = outs_o + ((size_t)t * Bz + b) * 1024;
        const size_t q = ((size_t)b * Tz + t) * Ez;
        for (int e = tid; e < Ez; e += 256) {
            float pmm = pm[e], plm = pm[Ez + e];
            float dm = qmm[q + e] - pmm;
            total += 0.5f * (plm - qlm[q + e]) + (__expf(qlm[q + e]) + dm * dm) / (2.f * __expf(plm)) - 0.5f;
            float pmo = po[e], plo = po[Ez + e];
            float dn = qmo[q + e] - pmo;
            total += 0.5f * (plo - qlo[q + e]) + (__expf(qlo[q + e]) + dn * dn) / (2.f * __expf(plo)) - 0.5f;
        }
    }
    __shared__ float red[256];
    red[tid] = total;
    __syncthreads();
    for (int s = 128; s > 0; s >>= 1) {
        if (tid < s) red[tid] += red[tid + s];
        __syncthreads();
    }
    if (tid == 0) out[b] = red[0];
}

extern "C" void kernel_launch(void* const* d_in, const int* in_sizes, int n_in,
                              void* d_out, int out_size, void* d_ws, size_t ws_size,
                              hipStream_t stream) {
    const float* obj_enc = (const float*)d_in[0];
    const int*   x       = (const int*)d_in[1];
    const float* qmm     = (const float*)d_in[2];
    const float* qlm     = (const float*)d_in[3];
    const float* qzm     = (const float*)d_in[4];
    const float* qmo     = (const float*)d_in[5];
    const float* qlo     = (const float*)d_in[6];
    const float* qzo     = (const float*)d_in[7];
    const float* emd     = (const float*)d_in[8];
    const float* W_ih_m  = (const float*)d_in[9];
    const float* W_hh_m  = (const float*)d_in[10];
    const float* b_m     = (const float*)d_in[11];
    const float* W_ih_o  = (const float*)d_in[12];
    const float* W_hh_o  = (const float*)d_in[13];
    const float* b_o     = (const float*)d_in[14];
    const float* fc_m_W  = (const float*)d_in[15];
    const float* fc_m_b  = (const float*)d_in[16];
    const float* fc_o_W  = (const float*)d_in[17];
    const float* fc_o_b  = (const float*)d_in[18];
    float* out = (float*)d_out;

    char* base = (char*)d_ws;
    size_t off = 0;
    auto alloc = [&](size_t bytes) { char* r = base + off; off += (bytes + 255) & ~(size_t)255; return r; };
    float* mask     = (float*)alloc((size_t)Bz * NOBJz * 4);
    u16* meanim_bf  = (u16*)alloc((size_t)Bz * Dz * 2);
    u16* Whh_m_bf   = (u16*)alloc((size_t)4 * HMz * HMz * 2);
    u16* Whh_o_bf   = (u16*)alloc((size_t)4 * HOz * HOz * 2);
    u16* Winp_m_bf  = (u16*)alloc((size_t)4 * HMz * KXM * 2);
    u16* Winp_o_bf  = (u16*)alloc((size_t)4 * HOz * KXO * 2);
    u16* Wmean_m_bf = (u16*)alloc((size_t)4 * HMz * Dz * 2);
    u16* Wmean_o_bf = (u16*)alloc((size_t)4 * HOz * Dz * 2);
    u16* Wfc_m_bf   = (u16*)alloc((size_t)1024 * HMz * 2);
    u16* Wfc_o_bf   = (u16*)alloc((size_t)1024 * HOz * 2);
    float* b_m_p    = (float*)alloc((size_t)4 * HMz * 4);
    float* b_o_p    = (float*)alloc((size_t)4 * HOz * 4);
    unsigned* bar   = (unsigned*)alloc(256);
    u16* Xin_m      = (u16*)alloc((size_t)Tz * Bz * KXM * 2);
    u16* Xin_o      = (u16*)alloc((size_t)Tz * Bz * KXO * 2);
    u16* const_m_bf = (u16*)alloc((size_t)Bz * 4 * HMz * 2);
    u16* const_o_bf = (u16*)alloc((size_t)Bz * 4 * HOz * 2);
    u16* Ginp_m_bf  = (u16*)alloc((size_t)Tz * Bz * 4 * HMz * 2);   // aliased by outs after loop
    u16* Ginp_o_bf  = (u16*)alloc((size_t)Tz * Bz * 4 * HOz * 2);
    u16* H_m        = (u16*)alloc((size_t)Tz * Bz * HMz * 2);
    u16* H_o        = (u16*)alloc((size_t)Tz * Bz * HOz * 2);
    float* outs_m = (float*)Ginp_m_bf;                              // 2 x 41.9MB inside 83.9MB
    float* outs_o = outs_m + (size_t)Tz * Bz * 1024;

    const int TB = Tz * Bz;

    hipMemsetAsync(bar, 0, 256, stream);    // barrier counter := 0 (capture-safe)

    obj_mask_kernel<<<Bz * NOBJz, 64, 0, stream>>>(obj_enc, mask);
    meanim_kernel<<<(Bz * Dz + 255) / 256, 256, 0, stream>>>(obj_enc, mask, meanim_bf);
    assemble_Xm<<<(TB * KXM + 255) / 256, 256, 0, stream>>>(Xin_m, qzm, x, emd);
    assemble_Xo<<<(TB * KXO + 255) / 256, 256, 0, stream>>>(Xin_o, qzm, qzo, x, emd);

    // weight conversions: LSTM weights get the gate-interleaved row permutation
    convert_pad<<<(4 * HMz * HMz + 255) / 256, 256, 0, stream>>>(Whh_m_bf, W_hh_m, 4 * HMz, HMz, HMz, 0, HMz, HMz);
    convert_pad<<<(4 * HOz * HOz + 255) / 256, 256, 0, stream>>>(Whh_o_bf, W_hh_o, 4 * HOz, HOz, HOz, 0, HOz, HOz);
    convert_pad<<<(4 * HMz * KXM + 255) / 256, 256, 0, stream>>>(Winp_m_bf, W_ih_m, 4 * HMz, Ez + EMBz, 2860, 0, KXM, HMz);
    convert_pad<<<(4 * HOz * KXO + 255) / 256, 256, 0, stream>>>(Winp_o_bf, W_ih_o, 4 * HOz, 2 * Ez + EMBz, 3372, 0, KXO, HOz);
    convert_pad<<<(4 * HMz * Dz + 255) / 256, 256, 0, stream>>>(Wmean_m_bf, W_ih_m, 4 * HMz, Dz, 2860, Ez + EMBz, Dz, HMz);
    convert_pad<<<(4 * HOz * Dz + 255) / 256, 256, 0, stream>>>(Wmean_o_bf, W_ih_o, 4 * HOz, Dz, 3372, 2 * Ez + EMBz, Dz, HOz);
    convert_pad<<<(1024 * HMz + 255) / 256, 256, 0, stream>>>(Wfc_m_bf, fc_m_W, 1024, HMz, HMz, 0, HMz, 0);
    convert_pad<<<(1024 * HOz + 255) / 256, 256, 0, stream>>>(Wfc_o_bf, fc_o_W, 1024, HOz, HOz, 0, HOz, 0);
    bias_perm<<<(4 * HMz + 255) / 256, 256, 0, stream>>>(b_m_p, b_m, HMz);
    bias_perm<<<(4 * HOz + 255) / 256, 256, 0, stream>>>(b_o_p, b_o, HOz);

    // const = bias + meanim projection (bf16, gate-interleaved cols)
    gemm128<<<dim3(4 * HMz / 128, Bz / 128), 256, 0, stream>>>(
        meanim_bf, Dz, Wmean_m_bf, Dz, const_m_bf, 4 * HMz, Dz, b_m_p, nullptr, 0u, 1);
    gemm128<<<dim3(4 * HOz / 128, Bz / 128), 256, 0, stream>>>(
        meanim_bf, Dz, Wmean_o_bf, Dz, const_o_bf, 4 * HOz, Dz, b_o_p, nullptr, 0u, 1);

    // Ginp = Xin @ Winp^T + const  (all T at once; addR row = global row & 511 = b)
    gemm128<<<dim3(4 * HMz / 128, TB / 128), 256, 0, stream>>>(
        Xin_m, KXM, Winp_m_bf, KXM, Ginp_m_bf, 4 * HMz, KXM, nullptr, const_m_bf, (unsigned)(Bz - 1), 1);
    gemm128<<<dim3(4 * HOz / 128, TB / 128), 256, 0, stream>>>(
        Xin_o, KXO, Winp_o_bf, KXO, Ginp_o_bf, 4 * HOz, KXO, nullptr, const_o_bf, (unsigned)(Bz - 1), 1);

    // all 20 recurrence steps in one persistent launch (160 blocks <= 256 CUs => all resident)
    step_persist<<<NBLK, 256, 0, stream>>>(
        H_m, Whh_m_bf, Ginp_m_bf, H_o, Whh_o_bf, Ginp_o_bf, bar);

    // FC heads over all (t,b) rows (normal column order, fp32 out)
    gemm128<<<dim3(1024 / 128, TB / 128), 256, 0, stream>>>(
        H_m, HMz, Wfc_m_bf, HMz, outs_m, 1024, HMz, fc_m_b, nullptr, 0u, 0);
    gemm128<<<dim3(1024 / 128, TB / 128), 256, 0, stream>>>(
        H_o, HOz, Wfc_o_bf, HOz, outs_o, 1024, HOz, fc_o_b, nullptr, 0u, 0);

    kl_kernel<<<Bz, 256, 0, stream>>>(outs_m, outs_o, qmm, qlm, qmo, qlo, x, out);
}